// Round 3
// baseline (294.155 us; speedup 1.0000x reference)
//
#include <hip/hip_runtime.h>
#include <hip/hip_bf16.h>
#include <stdint.h>

// Problem constants
#define BSZ 256
#define NQ 4096          // Q_SIZE
#define N1 8320          // GEMM1 padded N (130*64): [qkv_half 4096 | gate 4096 | alpha 32 | beta 32 | pad 64]
#define K1 2048
#define N3 2048
#define K3 4096

typedef __attribute__((ext_vector_type(8))) short bf16x8;
typedef __attribute__((ext_vector_type(4))) float f32x4;

__device__ __forceinline__ unsigned short f2bf(float f) {
  union { float f; unsigned u; } v; v.f = f;
  unsigned r = v.u + 0x7fffu + ((v.u >> 16) & 1u);   // RNE
  return (unsigned short)(r >> 16);
}

__device__ __forceinline__ bf16x8 pack8(float4 a, float4 b) {
  union { bf16x8 v; unsigned short u[8]; } o;
  o.u[0] = f2bf(a.x); o.u[1] = f2bf(a.y); o.u[2] = f2bf(a.z); o.u[3] = f2bf(a.w);
  o.u[4] = f2bf(b.x); o.u[5] = f2bf(b.y); o.u[6] = f2bf(b.z); o.u[7] = f2bf(b.w);
  return o.v;
}

// ---------------- K0: hidden fp32 -> bf16 ----------------
__global__ __launch_bounds__(256) void cvt_kernel(const float* __restrict__ x,
                                                  unsigned short* __restrict__ y) {
  int i = (blockIdx.x * 256 + threadIdx.x) * 8;
  float4 a = *(const float4*)(x + i);
  float4 b = *(const float4*)(x + i + 4);
  ushort4 o0 = { f2bf(a.x), f2bf(a.y), f2bf(a.z), f2bf(a.w) };
  ushort4 o1 = { f2bf(b.x), f2bf(b.y), f2bf(b.z), f2bf(b.w) };
  *(ushort4*)(y + i) = o0;
  *(ushort4*)(y + i + 4) = o1;
}

// ---------------- K1: GEMM1 (barrier-free, fragments direct from global) ----------------
// Block = 4 waves (2x2). Wave tile 64Mx32N. Block tile 128x64. Split-K=2 -> slabs.
__global__ __launch_bounds__(256, 2) void gemm1_kernel(
    const unsigned short* __restrict__ A16,   // [256][2048] bf16
    const float* __restrict__ Wqkv, const float* __restrict__ Wgate,
    const float* __restrict__ Walpha, const float* __restrict__ Wbeta,
    float* __restrict__ P) {                  // [2][256][8320] fp32 slabs
  const int tid = threadIdx.x, lane = tid & 63, wv = tid >> 6;
  const int wr = wv >> 1, wc = wv & 1;
  const int rt = blockIdx.x * 128;
  const int n0 = blockIdx.y * 64;
  const int kb = blockIdx.z * 1024;
  const int l15 = lane & 15, lk = (lane >> 4) * 8;

  const unsigned short* aptr[4];
#pragma unroll
  for (int i = 0; i < 4; i++)
    aptr[i] = A16 + (size_t)(rt + wr * 64 + i * 16 + l15) * K1 + kb + lk;
  const float* bptr[2];
#pragma unroll
  for (int j = 0; j < 2; j++) {
    int n = n0 + wc * 32 + j * 16 + l15;
    const float* s;
    if (n < 4096)       s = Wqkv  + (size_t)(4096 + n) * K1;
    else if (n < 8192)  s = Wgate + (size_t)(n - 4096) * K1;
    else if (n < 8224)  s = Walpha + (size_t)(n - 8192) * K1;
    else if (n < 8256)  s = Wbeta + (size_t)(n - 8224) * K1;
    else                s = Walpha;           // pad rows, never consumed
    bptr[j] = s + kb + lk;
  }

  f32x4 acc[4][2];
#pragma unroll
  for (int i = 0; i < 4; i++)
#pragma unroll
    for (int j = 0; j < 2; j++) { f32x4 z = {0.f, 0.f, 0.f, 0.f}; acc[i][j] = z; }

  bf16x8 aC[4]; float4 bC[2][2];
#pragma unroll
  for (int i = 0; i < 4; i++) aC[i] = *(const bf16x8*)(aptr[i]);
#pragma unroll
  for (int j = 0; j < 2; j++) {
    bC[j][0] = *(const float4*)(bptr[j]);
    bC[j][1] = *(const float4*)(bptr[j] + 4);
  }

#pragma unroll 2
  for (int ks = 0; ks < 32; ks++) {
    bf16x8 aN[4]; float4 bN[2][2];
    if (ks + 1 < 32) {
#pragma unroll
      for (int i = 0; i < 4; i++) aN[i] = *(const bf16x8*)(aptr[i] + (ks + 1) * 32);
#pragma unroll
      for (int j = 0; j < 2; j++) {
        bN[j][0] = *(const float4*)(bptr[j] + (ks + 1) * 32);
        bN[j][1] = *(const float4*)(bptr[j] + (ks + 1) * 32 + 4);
      }
    }
    bf16x8 bFr[2];
#pragma unroll
    for (int j = 0; j < 2; j++) bFr[j] = pack8(bC[j][0], bC[j][1]);
#pragma unroll
    for (int i = 0; i < 4; i++)
#pragma unroll
      for (int j = 0; j < 2; j++)
        acc[i][j] = __builtin_amdgcn_mfma_f32_16x16x32_bf16(aC[i], bFr[j], acc[i][j], 0, 0, 0);
#pragma unroll
    for (int i = 0; i < 4; i++) aC[i] = aN[i];
#pragma unroll
    for (int j = 0; j < 2; j++) { bC[j][0] = bN[j][0]; bC[j][1] = bN[j][1]; }
  }

  float* Pz = P + (size_t)blockIdx.z * ((size_t)BSZ * N1);
#pragma unroll
  for (int i = 0; i < 4; i++) {
    int row = rt + wr * 64 + i * 16 + (lane >> 4) * 4;
#pragma unroll
    for (int j = 0; j < 2; j++) {
      int col = n0 + wc * 32 + j * 16 + l15;
#pragma unroll
      for (int r = 0; r < 4; r++)
        Pz[(size_t)(row + r) * N1 + col] = acc[i][j][r];
    }
  }
}

// ---------------- K2: per-row fused conv + SSM + RMS + gate; writes core bf16 ----------------
__global__ __launch_bounds__(512) void fuse_kernel(
    const float* __restrict__ P,        // [2][256][8320]
    const float* __restrict__ bqkv,     // [8192]
    const float* __restrict__ ck,       // [8192][4]
    const float* __restrict__ cstate,   // [256][4][8192]
    const float* __restrict__ ssa,      // [32]
    const float* __restrict__ dtb,      // [32]
    const float* __restrict__ nw,       // [128]
    const float* __restrict__ sstate,   // [256][32]
    unsigned short* __restrict__ C16) { // [256][4096] bf16
  __shared__ __align__(16) float cb[4096];
  __shared__ float gsum[64];
  __shared__ float ssl[32];
  __shared__ float red[16];
  const int b = blockIdx.x, tid = threadIdx.x;
  const int lane = tid & 63, wv = tid >> 6;
  const float* P0 = P + (size_t)b * N1;
  const float* P1 = P + (size_t)(BSZ + b) * N1;

  if (wv == 0) {   // mean(ssm_norm_weight)
    float m = nw[lane] + nw[lane + 64];
#pragma unroll
    for (int off = 32; off; off >>= 1) m += __shfl_down(m, off, 64);
    if (lane == 0) red[8] = m * (1.f / 128.f);
  }

  // pass 1: core_base (conv) + group sums via 16-lane shuffle reduce
#pragma unroll
  for (int it = 0; it < 2; it++) {
    int j = (it * 512 + tid) * 4;
    float4 q0 = *(const float4*)(P0 + j);
    float4 q1 = *(const float4*)(P1 + j);
    float4 bq = *(const float4*)(bqkv + NQ + j);
    float mqx = q0.x + q1.x + bq.x, mqy = q0.y + q1.y + bq.y;
    float mqz = q0.z + q1.z + bq.z, mqw = q0.w + q1.w + bq.w;
    const float* csb = cstate + (size_t)b * 4 * 8192 + NQ + j;
    float4 c1 = *(const float4*)(csb + 8192);
    float4 c2 = *(const float4*)(csb + 16384);
    float4 c3 = *(const float4*)(csb + 24576);
    float4 k0v = *(const float4*)(ck + (size_t)(NQ + j) * 4);
    float4 k1v = *(const float4*)(ck + (size_t)(NQ + j + 1) * 4);
    float4 k2v = *(const float4*)(ck + (size_t)(NQ + j + 2) * 4);
    float4 k3v = *(const float4*)(ck + (size_t)(NQ + j + 3) * 4);
    float4 cbv;
    cbv.x = c1.x * k0v.x + c2.x * k0v.y + c3.x * k0v.z + mqx * k0v.w;
    cbv.y = c1.y * k1v.x + c2.y * k1v.y + c3.y * k1v.z + mqy * k1v.w;
    cbv.z = c1.z * k2v.x + c2.z * k2v.y + c3.z * k2v.z + mqz * k2v.w;
    cbv.w = c1.w * k3v.x + c2.w * k3v.y + c3.w * k3v.z + mqw * k3v.w;
    *(float4*)(cb + j) = cbv;
    float s = cbv.x + cbv.y + cbv.z + cbv.w;
    s += __shfl_xor(s, 1, 64); s += __shfl_xor(s, 2, 64);
    s += __shfl_xor(s, 4, 64); s += __shfl_xor(s, 8, 64);
    if ((lane & 15) == 0) gsum[(it * 512 + tid) >> 4] = s;
  }
  __syncthreads();

  if (tid < 32) {
    float a  = P0[8192 + tid] + P1[8192 + tid];
    float bc = P0[8224 + tid] + P1[8224 + tid];
    float kg = gsum[tid] * (1.f / 64.f);
    float vg = gsum[32 + tid] * (1.f / 64.f);
    float x = a + dtb[tid];
    float sp = fmaxf(x, 0.f) + log1pf(expf(-fabsf(x)));   // stable softplus
    float g = -expf(ssa[tid]) * sp;
    float beta = 1.f / (1.f + expf(-bc));
    float ns = expf(g) * sstate[b * 32 + tid] + beta * vg;
    ssl[tid] = ns / (1.f + expf(-kg));
  }
  __syncthreads();

  // pass 2: core1 = core_base + expanded; sum of squares
  float sq = 0.f;
  float4 c1r[2];
#pragma unroll
  for (int it = 0; it < 2; it++) {
    int j = (it * 512 + tid) * 4;
    float4 v = *(const float4*)(cb + j);
    float sv = ssl[j >> 7];
    v.x += sv; v.y += sv; v.z += sv; v.w += sv;
    c1r[it] = v;
    sq += v.x * v.x + v.y * v.y + v.z * v.z + v.w * v.w;
  }
#pragma unroll
  for (int off = 32; off; off >>= 1) sq += __shfl_down(sq, off, 64);
  if (lane == 0) red[wv] = sq;
  __syncthreads();
  if (tid == 0) {
    float t = red[0] + red[1] + red[2] + red[3] + red[4] + red[5] + red[6] + red[7];
    red[9] = rsqrtf(t * (1.f / 4096.f) + 1e-6f);
  }
  __syncthreads();
  float rms = red[9], mwv = red[8];

  // pass 3: apply gate, write bf16
#pragma unroll
  for (int it = 0; it < 2; it++) {
    int j = (it * 512 + tid) * 4;
    float4 g0x = *(const float4*)(P0 + NQ + j);
    float4 g1x = *(const float4*)(P1 + NQ + j);
    float4 v = c1r[it];
    float ox = v.x * rms * mwv / (1.f + expf(-(g0x.x + g1x.x)));
    float oy = v.y * rms * mwv / (1.f + expf(-(g0x.y + g1x.y)));
    float oz = v.z * rms * mwv / (1.f + expf(-(g0x.z + g1x.z)));
    float ow = v.w * rms * mwv / (1.f + expf(-(g0x.w + g1x.w)));
    ushort4 u = { f2bf(ox), f2bf(oy), f2bf(oz), f2bf(ow) };
    *(ushort4*)(C16 + (size_t)b * 4096 + j) = u;
  }
}

// ---------------- K3: GEMM3 (barrier-free), split-K=8 -> 8 slabs ----------------
__global__ __launch_bounds__(256, 2) void gemm3_kernel(
    const unsigned short* __restrict__ A16,  // core [256][4096] bf16
    const float* __restrict__ Wout,          // [2048][4096] fp32
    float* __restrict__ OP) {                // [8][256][2048] fp32 slabs
  const int tid = threadIdx.x, lane = tid & 63, wv = tid >> 6;
  const int wr = wv >> 1, wc = wv & 1;
  const int rt = blockIdx.x * 128;
  const int n0 = blockIdx.y * 64;
  const int kb = blockIdx.z * 512;
  const int l15 = lane & 15, lk = (lane >> 4) * 8;

  const unsigned short* aptr[4];
#pragma unroll
  for (int i = 0; i < 4; i++)
    aptr[i] = A16 + (size_t)(rt + wr * 64 + i * 16 + l15) * K3 + kb + lk;
  const float* bptr[2];
#pragma unroll
  for (int j = 0; j < 2; j++)
    bptr[j] = Wout + (size_t)(n0 + wc * 32 + j * 16 + l15) * K3 + kb + lk;

  f32x4 acc[4][2];
#pragma unroll
  for (int i = 0; i < 4; i++)
#pragma unroll
    for (int j = 0; j < 2; j++) { f32x4 z = {0.f, 0.f, 0.f, 0.f}; acc[i][j] = z; }

  bf16x8 aC[4]; float4 bC[2][2];
#pragma unroll
  for (int i = 0; i < 4; i++) aC[i] = *(const bf16x8*)(aptr[i]);
#pragma unroll
  for (int j = 0; j < 2; j++) {
    bC[j][0] = *(const float4*)(bptr[j]);
    bC[j][1] = *(const float4*)(bptr[j] + 4);
  }

#pragma unroll 2
  for (int ks = 0; ks < 16; ks++) {
    bf16x8 aN[4]; float4 bN[2][2];
    if (ks + 1 < 16) {
#pragma unroll
      for (int i = 0; i < 4; i++) aN[i] = *(const bf16x8*)(aptr[i] + (ks + 1) * 32);
#pragma unroll
      for (int j = 0; j < 2; j++) {
        bN[j][0] = *(const float4*)(bptr[j] + (ks + 1) * 32);
        bN[j][1] = *(const float4*)(bptr[j] + (ks + 1) * 32 + 4);
      }
    }
    bf16x8 bFr[2];
#pragma unroll
    for (int j = 0; j < 2; j++) bFr[j] = pack8(bC[j][0], bC[j][1]);
#pragma unroll
    for (int i = 0; i < 4; i++)
#pragma unroll
      for (int j = 0; j < 2; j++)
        acc[i][j] = __builtin_amdgcn_mfma_f32_16x16x32_bf16(aC[i], bFr[j], acc[i][j], 0, 0, 0);
#pragma unroll
    for (int i = 0; i < 4; i++) aC[i] = aN[i];
#pragma unroll
    for (int j = 0; j < 2; j++) { bC[j][0] = bN[j][0]; bC[j][1] = bN[j][1]; }
  }

  float* Oz = OP + (size_t)blockIdx.z * ((size_t)BSZ * N3);
#pragma unroll
  for (int i = 0; i < 4; i++) {
    int row = rt + wr * 64 + i * 16 + (lane >> 4) * 4;
#pragma unroll
    for (int j = 0; j < 2; j++) {
      int col = n0 + wc * 32 + j * 16 + l15;
#pragma unroll
      for (int r = 0; r < 4; r++)
        Oz[(size_t)(row + r) * N3 + col] = acc[i][j][r];
    }
  }
}

// ---------------- K4: reduce 8 slabs -> out ----------------
__global__ __launch_bounds__(256) void reduce_kernel(const float* __restrict__ OP,
                                                     float* __restrict__ out) {
  int i = (blockIdx.x * 256 + threadIdx.x) * 4;
  float4 s = *(const float4*)(OP + i);
#pragma unroll
  for (int z = 1; z < 8; z++) {
    float4 v = *(const float4*)(OP + (size_t)z * BSZ * N3 + i);
    s.x += v.x; s.y += v.y; s.z += v.z; s.w += v.w;
  }
  *(float4*)(out + i) = s;
}

extern "C" void kernel_launch(void* const* d_in, const int* in_sizes, int n_in,
                              void* d_out, int out_size, void* d_ws, size_t ws_size,
                              hipStream_t stream) {
  const float* hidden = (const float*)d_in[0];
  const float* Wqkv   = (const float*)d_in[1];
  const float* bqkv   = (const float*)d_in[2];
  const float* Wgate  = (const float*)d_in[3];
  const float* Walpha = (const float*)d_in[4];
  const float* Wbeta  = (const float*)d_in[5];
  const float* Wout   = (const float*)d_in[6];
  const float* ssa    = (const float*)d_in[7];
  const float* dtb    = (const float*)d_in[8];
  const float* nw     = (const float*)d_in[9];
  const float* ck     = (const float*)d_in[10];
  const float* sstate = (const float*)d_in[11];
  const float* cstate = (const float*)d_in[12];
  float* out = (float*)d_out;

  char* ws = (char*)d_ws;
  unsigned short* A16 = (unsigned short*)ws;                       // 1 MB
  float* P   = (float*)(ws + (1 << 20));                           // 2*256*8320*4 = 17,039,360 B
  unsigned short* C16 = (unsigned short*)(ws + (1 << 20) + 17039360);  // 2 MB
  float* OP  = (float*)(ws + (1 << 20) + 17039360 + (2 << 20));    // 8*256*2048*4 = 16 MB

  cvt_kernel<<<256, 256, 0, stream>>>(hidden, A16);
  gemm1_kernel<<<dim3(2, 130, 2), 256, 0, stream>>>(A16, Wqkv, Wgate, Walpha, Wbeta, P);
  fuse_kernel<<<256, 512, 0, stream>>>(P, bqkv, ck, cstate, ssa, dtb, nw, sstate, C16);
  gemm3_kernel<<<dim3(2, 32, 8), 256, 0, stream>>>(C16, Wout, OP);
  reduce_kernel<<<512, 256, 0, stream>>>(OP, out);
}

// Round 4
// 233.420 us; speedup vs baseline: 1.2602x; 1.2602x over previous
//
#include <hip/hip_runtime.h>
#include <hip/hip_bf16.h>
#include <stdint.h>

// Problem constants
#define BSZ 256
#define NQ 4096          // Q_SIZE
#define N1 8320          // GEMM1 padded N: [qkv_half 4096 | gate 4096 | alpha 32 | beta 32 | pad 64]
#define K1 2048
#define N3 2048
#define K3 4096

typedef __attribute__((ext_vector_type(8))) short bf16x8;
typedef __attribute__((ext_vector_type(4))) float f32x4;

__device__ __forceinline__ unsigned short f2bf(float f) {
  union { float f; unsigned u; } v; v.f = f;
  unsigned r = v.u + 0x7fffu + ((v.u >> 16) & 1u);   // RNE
  return (unsigned short)(r >> 16);
}

__device__ __forceinline__ bf16x8 pack8(float4 a, float4 b) {
  union { bf16x8 v; unsigned short u[8]; } o;
  o.u[0] = f2bf(a.x); o.u[1] = f2bf(a.y); o.u[2] = f2bf(a.z); o.u[3] = f2bf(a.w);
  o.u[4] = f2bf(b.x); o.u[5] = f2bf(b.y); o.u[6] = f2bf(b.z); o.u[7] = f2bf(b.w);
  return o.v;
}

__device__ __forceinline__ void gload_lds16(const void* g, void* lds_uniform) {
  __builtin_amdgcn_global_load_lds(
      (const __attribute__((address_space(1))) unsigned int*)g,
      (__attribute__((address_space(3))) unsigned int*)lds_uniform, 16, 0, 0);
}

// ---------------- K0: hidden fp32 -> bf16 ----------------
__global__ __launch_bounds__(256) void cvt_kernel(const float* __restrict__ x,
                                                  unsigned short* __restrict__ y) {
  int i = (blockIdx.x * 256 + threadIdx.x) * 8;
  float4 a = *(const float4*)(x + i);
  float4 b = *(const float4*)(x + i + 4);
  ushort4 o0 = { f2bf(a.x), f2bf(a.y), f2bf(a.z), f2bf(a.w) };
  ushort4 o1 = { f2bf(b.x), f2bf(b.y), f2bf(b.z), f2bf(b.w) };
  *(ushort4*)(y + i) = o0;
  *(ushort4*)(y + i + 4) = o1;
}

// ================= GEMM core (shared structure) =================
// Tile: M128 x N32, BK=64 fp32-B / bf16-A, single-buffer LDS, all staging via
// global_load_lds DMA with XOR-swizzled source so ds_reads are conflict-free.
// sA: row m (128) x 8 chunks of 16B; phys chunk = c ^ (m&7)   (16 KB)
// sB: row n (32)  x 16 chunks of 16B; phys chunk = c ^ (n&15)  (8 KB)

// ---------------- K1: GEMM1  P[z] = hidden @ [Wqkv_half;Wgate;Walpha;Wbeta]^T ----------------
__global__ __launch_bounds__(256, 4) void gemm1_kernel(
    const unsigned short* __restrict__ A16,   // [256][2048] bf16
    const float* __restrict__ Wqkv, const float* __restrict__ Wgate,
    const float* __restrict__ Walpha, const float* __restrict__ Wbeta,
    float* __restrict__ P) {                  // [2][256][8320] fp32 slabs
  __shared__ __align__(16) unsigned short sA[128 * 64];
  __shared__ __align__(16) float sB[32 * 64];
  const int tid = threadIdx.x, lane = tid & 63, wv = tid >> 6;
  const int wr = wv >> 1, wc = wv & 1, l15 = lane & 15;
  const int rt = blockIdx.x * 128;
  const int n0 = blockIdx.y * 32;
  const int kb = blockIdx.z * 1024;

  // A DMA: 16 instrs (4/wave). instr s covers rows 8s..8s+7, lane = row(l>>3), chunk p=l&7
  const char* aS[4]; char* aD[4];
#pragma unroll
  for (int t = 0; t < 4; t++) {
    int s = wv * 4 + t;
    int m = 8 * s + (lane >> 3);
    int c = (lane & 7) ^ ((lane >> 3) & 7);           // logical chunk for phys slot
    aS[t] = (const char*)(A16 + (size_t)(rt + m) * K1 + kb) + c * 16;
    aD[t] = (char*)sA + s * 1024;
  }
  // B DMA: 8 instrs (2/wave). instr s covers rows 4s..4s+3, lane = row(l>>4), chunk p=l&15
  const char* bS[2]; char* bD[2];
#pragma unroll
  for (int t = 0; t < 2; t++) {
    int s = wv * 2 + t;
    int n = 4 * s + (lane >> 4);
    int c = (lane & 15) ^ (n & 15);
    int ng = n0 + n;
    const float* base;
    if (ng < 4096)       base = Wqkv  + (size_t)(4096 + ng) * K1;
    else if (ng < 8192)  base = Wgate + (size_t)(ng - 4096) * K1;
    else if (ng < 8224)  base = Walpha + (size_t)(ng - 8192) * K1;
    else if (ng < 8256)  base = Wbeta + (size_t)(ng - 8224) * K1;
    else                 base = Walpha;                // pad rows, never consumed
    bS[t] = (const char*)(base + kb) + c * 16;
    bD[t] = (char*)sB + s * 1024;
  }

  f32x4 acc[4];
#pragma unroll
  for (int i = 0; i < 4; i++) { f32x4 z = {0.f, 0.f, 0.f, 0.f}; acc[i] = z; }

  for (int it = 0; it < 16; it++) {
    __syncthreads();                                   // LDS free (prev compute done)
#pragma unroll
    for (int t = 0; t < 4; t++) gload_lds16(aS[t] + it * 128, aD[t]);
#pragma unroll
    for (int t = 0; t < 2; t++) gload_lds16(bS[t] + it * 256, bD[t]);
    __syncthreads();                                   // staged (vmcnt drained)
#pragma unroll
    for (int ks2 = 0; ks2 < 2; ks2++) {
      int nr = wc * 16 + l15;
      int c0 = ks2 * 8 + (lane >> 4) * 2;
      float4 b0 = *(const float4*)((const char*)sB + nr * 256 + ((c0 ^ (nr & 15)) * 16));
      float4 b1 = *(const float4*)((const char*)sB + nr * 256 + (((c0 + 1) ^ (nr & 15)) * 16));
      bf16x8 bF = pack8(b0, b1);
#pragma unroll
      for (int i = 0; i < 4; i++) {
        int m = wr * 64 + i * 16 + l15;
        int cA = ks2 * 4 + (lane >> 4);
        bf16x8 aF = *(const bf16x8*)((const char*)sA + m * 128 + ((cA ^ (m & 7)) * 16));
        acc[i] = __builtin_amdgcn_mfma_f32_16x16x32_bf16(aF, bF, acc[i], 0, 0, 0);
      }
    }
  }

  float* Pz = P + (size_t)blockIdx.z * ((size_t)BSZ * N1);
#pragma unroll
  for (int i = 0; i < 4; i++) {
    int row = rt + wr * 64 + i * 16 + (lane >> 4) * 4;
    int col = n0 + wc * 16 + l15;
#pragma unroll
    for (int r = 0; r < 4; r++)
      Pz[(size_t)(row + r) * N1 + col] = acc[i][r];
  }
}

// ---------------- K2: per-row fused conv + SSM + RMS + gate; writes core bf16 ----------------
__global__ __launch_bounds__(512) void fuse_kernel(
    const float* __restrict__ P,        // [2][256][8320]
    const float* __restrict__ bqkv,     // [8192]
    const float* __restrict__ ck,       // [8192][4]
    const float* __restrict__ cstate,   // [256][4][8192]
    const float* __restrict__ ssa,      // [32]
    const float* __restrict__ dtb,      // [32]
    const float* __restrict__ nw,       // [128]
    const float* __restrict__ sstate,   // [256][32]
    unsigned short* __restrict__ C16) { // [256][4096] bf16
  __shared__ __align__(16) float cb[4096];
  __shared__ float gsum[64];
  __shared__ float ssl[32];
  __shared__ float red[16];
  const int b = blockIdx.x, tid = threadIdx.x;
  const int lane = tid & 63, wv = tid >> 6;
  const float* P0 = P + (size_t)b * N1;
  const float* P1 = P + (size_t)(BSZ + b) * N1;

  if (wv == 0) {   // mean(ssm_norm_weight)
    float m = nw[lane] + nw[lane + 64];
#pragma unroll
    for (int off = 32; off; off >>= 1) m += __shfl_down(m, off, 64);
    if (lane == 0) red[8] = m * (1.f / 128.f);
  }

  // pass 1: core_base (conv) + group sums via 16-lane shuffle reduce
#pragma unroll
  for (int it = 0; it < 2; it++) {
    int j = (it * 512 + tid) * 4;
    float4 q0 = *(const float4*)(P0 + j);
    float4 q1 = *(const float4*)(P1 + j);
    float4 bq = *(const float4*)(bqkv + NQ + j);
    float mqx = q0.x + q1.x + bq.x, mqy = q0.y + q1.y + bq.y;
    float mqz = q0.z + q1.z + bq.z, mqw = q0.w + q1.w + bq.w;
    const float* csb = cstate + (size_t)b * 4 * 8192 + NQ + j;
    float4 c1 = *(const float4*)(csb + 8192);
    float4 c2 = *(const float4*)(csb + 16384);
    float4 c3 = *(const float4*)(csb + 24576);
    float4 k0v = *(const float4*)(ck + (size_t)(NQ + j) * 4);
    float4 k1v = *(const float4*)(ck + (size_t)(NQ + j + 1) * 4);
    float4 k2v = *(const float4*)(ck + (size_t)(NQ + j + 2) * 4);
    float4 k3v = *(const float4*)(ck + (size_t)(NQ + j + 3) * 4);
    float4 cbv;
    cbv.x = c1.x * k0v.x + c2.x * k0v.y + c3.x * k0v.z + mqx * k0v.w;
    cbv.y = c1.y * k1v.x + c2.y * k1v.y + c3.y * k1v.z + mqy * k1v.w;
    cbv.z = c1.z * k2v.x + c2.z * k2v.y + c3.z * k2v.z + mqz * k2v.w;
    cbv.w = c1.w * k3v.x + c2.w * k3v.y + c3.w * k3v.z + mqw * k3v.w;
    *(float4*)(cb + j) = cbv;
    float s = cbv.x + cbv.y + cbv.z + cbv.w;
    s += __shfl_xor(s, 1, 64); s += __shfl_xor(s, 2, 64);
    s += __shfl_xor(s, 4, 64); s += __shfl_xor(s, 8, 64);
    if ((lane & 15) == 0) gsum[(it * 512 + tid) >> 4] = s;
  }
  __syncthreads();

  if (tid < 32) {
    float a  = P0[8192 + tid] + P1[8192 + tid];
    float bc = P0[8224 + tid] + P1[8224 + tid];
    float kg = gsum[tid] * (1.f / 64.f);
    float vg = gsum[32 + tid] * (1.f / 64.f);
    float x = a + dtb[tid];
    float sp = fmaxf(x, 0.f) + log1pf(expf(-fabsf(x)));   // stable softplus
    float g = -expf(ssa[tid]) * sp;
    float beta = 1.f / (1.f + expf(-bc));
    float ns = expf(g) * sstate[b * 32 + tid] + beta * vg;
    ssl[tid] = ns / (1.f + expf(-kg));
  }
  __syncthreads();

  // pass 2: core1 = core_base + expanded; sum of squares
  float sq = 0.f;
  float4 c1r[2];
#pragma unroll
  for (int it = 0; it < 2; it++) {
    int j = (it * 512 + tid) * 4;
    float4 v = *(const float4*)(cb + j);
    float sv = ssl[j >> 7];
    v.x += sv; v.y += sv; v.z += sv; v.w += sv;
    c1r[it] = v;
    sq += v.x * v.x + v.y * v.y + v.z * v.z + v.w * v.w;
  }
#pragma unroll
  for (int off = 32; off; off >>= 1) sq += __shfl_down(sq, off, 64);
  if (lane == 0) red[wv] = sq;
  __syncthreads();
  if (tid == 0) {
    float t = red[0] + red[1] + red[2] + red[3] + red[4] + red[5] + red[6] + red[7];
    red[9] = rsqrtf(t * (1.f / 4096.f) + 1e-6f);
  }
  __syncthreads();
  float rms = red[9], mwv = red[8];

  // pass 3: apply gate, write bf16
#pragma unroll
  for (int it = 0; it < 2; it++) {
    int j = (it * 512 + tid) * 4;
    float4 g0x = *(const float4*)(P0 + NQ + j);
    float4 g1x = *(const float4*)(P1 + NQ + j);
    float4 v = c1r[it];
    float ox = v.x * rms * mwv / (1.f + expf(-(g0x.x + g1x.x)));
    float oy = v.y * rms * mwv / (1.f + expf(-(g0x.y + g1x.y)));
    float oz = v.z * rms * mwv / (1.f + expf(-(g0x.z + g1x.z)));
    float ow = v.w * rms * mwv / (1.f + expf(-(g0x.w + g1x.w)));
    ushort4 u = { f2bf(ox), f2bf(oy), f2bf(oz), f2bf(ow) };
    *(ushort4*)(C16 + (size_t)b * 4096 + j) = u;
  }
}

// ---------------- K3: GEMM3 OP[z] = core @ Wout^T (split-K=8 slabs) ----------------
__global__ __launch_bounds__(256, 4) void gemm3_kernel(
    const unsigned short* __restrict__ A16,  // core [256][4096] bf16
    const float* __restrict__ Wout,          // [2048][4096] fp32
    float* __restrict__ OP) {                // [8][256][2048] fp32 slabs
  __shared__ __align__(16) unsigned short sA[128 * 64];
  __shared__ __align__(16) float sB[32 * 64];
  const int tid = threadIdx.x, lane = tid & 63, wv = tid >> 6;
  const int wr = wv >> 1, wc = wv & 1, l15 = lane & 15;
  const int rt = blockIdx.x * 128;
  const int n0 = blockIdx.y * 32;
  const int kb = blockIdx.z * 512;

  const char* aS[4]; char* aD[4];
#pragma unroll
  for (int t = 0; t < 4; t++) {
    int s = wv * 4 + t;
    int m = 8 * s + (lane >> 3);
    int c = (lane & 7) ^ ((lane >> 3) & 7);
    aS[t] = (const char*)(A16 + (size_t)(rt + m) * K3 + kb) + c * 16;
    aD[t] = (char*)sA + s * 1024;
  }
  const char* bS[2]; char* bD[2];
#pragma unroll
  for (int t = 0; t < 2; t++) {
    int s = wv * 2 + t;
    int n = 4 * s + (lane >> 4);
    int c = (lane & 15) ^ (n & 15);
    bS[t] = (const char*)(Wout + (size_t)(n0 + n) * K3 + kb) + c * 16;
    bD[t] = (char*)sB + s * 1024;
  }

  f32x4 acc[4];
#pragma unroll
  for (int i = 0; i < 4; i++) { f32x4 z = {0.f, 0.f, 0.f, 0.f}; acc[i] = z; }

  for (int it = 0; it < 8; it++) {
    __syncthreads();
#pragma unroll
    for (int t = 0; t < 4; t++) gload_lds16(aS[t] + it * 128, aD[t]);
#pragma unroll
    for (int t = 0; t < 2; t++) gload_lds16(bS[t] + it * 256, bD[t]);
    __syncthreads();
#pragma unroll
    for (int ks2 = 0; ks2 < 2; ks2++) {
      int nr = wc * 16 + l15;
      int c0 = ks2 * 8 + (lane >> 4) * 2;
      float4 b0 = *(const float4*)((const char*)sB + nr * 256 + ((c0 ^ (nr & 15)) * 16));
      float4 b1 = *(const float4*)((const char*)sB + nr * 256 + (((c0 + 1) ^ (nr & 15)) * 16));
      bf16x8 bF = pack8(b0, b1);
#pragma unroll
      for (int i = 0; i < 4; i++) {
        int m = wr * 64 + i * 16 + l15;
        int cA = ks2 * 4 + (lane >> 4);
        bf16x8 aF = *(const bf16x8*)((const char*)sA + m * 128 + ((cA ^ (m & 7)) * 16));
        acc[i] = __builtin_amdgcn_mfma_f32_16x16x32_bf16(aF, bF, acc[i], 0, 0, 0);
      }
    }
  }

  float* Oz = OP + (size_t)blockIdx.z * ((size_t)BSZ * N3);
#pragma unroll
  for (int i = 0; i < 4; i++) {
    int row = rt + wr * 64 + i * 16 + (lane >> 4) * 4;
    int col = n0 + wc * 16 + l15;
#pragma unroll
    for (int r = 0; r < 4; r++)
      Oz[(size_t)(row + r) * N3 + col] = acc[i][r];
  }
}

// ---------------- K4: reduce 8 slabs -> out ----------------
__global__ __launch_bounds__(256) void reduce_kernel(const float* __restrict__ OP,
                                                     float* __restrict__ out) {
  int i = (blockIdx.x * 256 + threadIdx.x) * 4;
  float4 s = *(const float4*)(OP + i);
#pragma unroll
  for (int z = 1; z < 8; z++) {
    float4 v = *(const float4*)(OP + (size_t)z * BSZ * N3 + i);
    s.x += v.x; s.y += v.y; s.z += v.z; s.w += v.w;
  }
  *(float4*)(out + i) = s;
}

extern "C" void kernel_launch(void* const* d_in, const int* in_sizes, int n_in,
                              void* d_out, int out_size, void* d_ws, size_t ws_size,
                              hipStream_t stream) {
  const float* hidden = (const float*)d_in[0];
  const float* Wqkv   = (const float*)d_in[1];
  const float* bqkv   = (const float*)d_in[2];
  const float* Wgate  = (const float*)d_in[3];
  const float* Walpha = (const float*)d_in[4];
  const float* Wbeta  = (const float*)d_in[5];
  const float* Wout   = (const float*)d_in[6];
  const float* ssa    = (const float*)d_in[7];
  const float* dtb    = (const float*)d_in[8];
  const float* nw     = (const float*)d_in[9];
  const float* ck     = (const float*)d_in[10];
  const float* sstate = (const float*)d_in[11];
  const float* cstate = (const float*)d_in[12];
  float* out = (float*)d_out;

  char* ws = (char*)d_ws;
  unsigned short* A16 = (unsigned short*)ws;                           // 1 MB
  float* P   = (float*)(ws + (1 << 20));                               // 2*256*8320*4 = 17,039,360 B
  unsigned short* C16 = (unsigned short*)(ws + (1 << 20) + 17039360);  // 2 MB
  float* OP  = (float*)(ws + (1 << 20) + 17039360 + (2 << 20));        // 8*256*2048*4 = 16 MB

  cvt_kernel<<<256, 256, 0, stream>>>(hidden, A16);
  gemm1_kernel<<<dim3(2, 260, 2), 256, 0, stream>>>(A16, Wqkv, Wgate, Walpha, Wbeta, P);
  fuse_kernel<<<256, 512, 0, stream>>>(P, bqkv, ck, cstate, ssa, dtb, nw, sstate, C16);
  gemm3_kernel<<<dim3(2, 64, 8), 256, 0, stream>>>(C16, Wout, OP);
  reduce_kernel<<<512, 256, 0, stream>>>(OP, out);
}